// Round 1
// baseline (28.431 us; speedup 1.0000x reference)
//
#include <hip/hip_runtime.h>

// Soft decision forest, depth=4, W=4: B=256, T=64, N=341 nodes, 1024 leaves.
// Output[b,t,L] = prod_{l=0..4} softmax(in[b,t,n_l,:])[j_l],
// L = j0*256 + j1*64 + j2*16 + j3*4 + j4, preorder node indices:
// n0=0, n1=1+85*j0, n2=n1+1+21*j1, n3=n2+1+5*j2, n4=n3+1+j3.

#define NUM_NODES 341

__global__ __launch_bounds__(256) void forest_kernel(const float* __restrict__ in,
                                                     float* __restrict__ out) {
    __shared__ float4 sP[NUM_NODES];  // 5456 B: softmax probs per node

    const int bt  = blockIdx.x;       // (b*T + t), 0..16383
    const int tid = threadIdx.x;      // 0..255

    // ---- Phase 1: softmax over W=4 per node, coalesced float4 loads ----
    const float4* in4 = reinterpret_cast<const float4*>(in) + (size_t)bt * NUM_NODES;
    for (int n = tid; n < NUM_NODES; n += 256) {
        float4 v = in4[n];
        float m  = fmaxf(fmaxf(v.x, v.y), fmaxf(v.z, v.w));
        float e0 = __expf(v.x - m);
        float e1 = __expf(v.y - m);
        float e2 = __expf(v.z - m);
        float e3 = __expf(v.w - m);
        float r  = 1.0f / (e0 + e1 + e2 + e3);
        sP[n] = make_float4(e0 * r, e1 * r, e2 * r, e3 * r);
    }
    __syncthreads();

    // ---- Phase 2: each thread computes 4 consecutive leaves (shared n4) ----
    const float* sPf = reinterpret_cast<const float*>(sP);
    const int j0 =  tid >> 6;
    const int j1 = (tid >> 4) & 3;
    const int j2 = (tid >> 2) & 3;
    const int j3 =  tid & 3;

    const int n1 = 1 + j0 * 85;
    const int n2 = n1 + 1 + j1 * 21;
    const int n3 = n2 + 1 + j2 * 5;
    const int n4 = n3 + 1 + j3;

    const float pre = sPf[j0]            // root node 0, branch j0
                    * sPf[n1 * 4 + j1]
                    * sPf[n2 * 4 + j2]
                    * sPf[n3 * 4 + j3];

    float4 pv = sP[n4];
    float4 o  = make_float4(pre * pv.x, pre * pv.y, pre * pv.z, pre * pv.w);

    reinterpret_cast<float4*>(out)[(size_t)bt * 256 + tid] = o;
}

extern "C" void kernel_launch(void* const* d_in, const int* in_sizes, int n_in,
                              void* d_out, int out_size, void* d_ws, size_t ws_size,
                              hipStream_t stream) {
    const float* in = (const float*)d_in[0];
    float* out = (float*)d_out;
    const int num_bt = 256 * 64;  // B * T
    forest_kernel<<<num_bt, 256, 0, stream>>>(in, out);
}